// Round 1
// baseline (1077.014 us; speedup 1.0000x reference)
//
#include <hip/hip_runtime.h>

#define E 256
#define OUTD 128
#define KSTEPS 128

typedef short bf16x8 __attribute__((ext_vector_type(8)));
typedef float f32x4 __attribute__((ext_vector_type(4)));
typedef unsigned short ushort_t;
typedef unsigned int uint_t;

__device__ __forceinline__ ushort_t f2bf(float f){
  union { float f; uint_t u; } v; v.f = f;
  uint_t r = (v.u + 0x7FFFu + ((v.u >> 16) & 1u)) >> 16;
  return (ushort_t)r;
}
__device__ __forceinline__ float sigmoid_(float x){ return 1.f/(1.f + __expf(-x)); }
__device__ __forceinline__ float tanh_(float x){ return 2.f/(1.f + __expf(-2.f*x)) - 1.f; }

// ---------------------------------------------------------------------------
// Prep: build bf16 weight-fragment arrays in ws.
//   Wc (steps>=1): [r+z combined | W_ih_n | W_hh_n]  -> G cols [0,1024)
//   W0 (step 0):   [W_hh_r | W_hh_z | 0 | W_hh_n]
//   Wo:            W_out fragments
// Fragment layout: frag(t,kk,l,j) = W[k][c], c = t*16 + (l&15),
//                  k = kk*32 + (l>>4)*8 + j   (consistent with A-frag reads,
//                  so any HW intra-k permutation cancels)
// ---------------------------------------------------------------------------
__global__ void prep_weights(const float* __restrict__ W_ih,
                             const float* __restrict__ W_hh,
                             const float* __restrict__ W_out,
                             ushort_t* __restrict__ ws)
{
  int fragIdx = blockIdx.x * blockDim.x + threadIdx.x;  // 0..69631
  if (fragIdx >= 69632) return;
  int arr, f;
  if (fragIdx < 32768)      { arr = 0; f = fragIdx; }
  else if (fragIdx < 65536) { arr = 1; f = fragIdx - 32768; }
  else                      { arr = 2; f = fragIdx - 65536; }
  int l  = f & 63;
  int tk = f >> 6;
  int kk = tk & 7;
  int t  = tk >> 3;
  int c  = t*16 + (l & 15);
  int kbase = kk*32 + (l >> 4)*8;
  bf16x8 v8;
#pragma unroll
  for (int j = 0; j < 8; j++){
    int k = kbase + j;
    float v;
    if (arr == 0){
      v = (c < 512) ? (W_ih[c*E + k] + W_hh[c*E + k])
        : (c < 768) ? W_ih[c*E + k]
                    : W_hh[(c-256)*E + k];
    } else if (arr == 1){
      v = (c < 512) ? W_hh[c*E + k]
        : (c < 768) ? 0.f
                    : W_hh[(c-256)*E + k];
    } else {
      v = W_out[c*E + k];
    }
    v8[j] = (short)f2bf(v);
  }
  *reinterpret_cast<bf16x8*>(ws + (size_t)fragIdx * 8) = v8;
}

// ---------------------------------------------------------------------------
// Main persistent kernel: 128 blocks x 512 threads (8 waves).
// Block b owns rows [16b, 16b+16). Wave w owns E-cols [32w, 32w+32) of all
// 4 gate parts (8 G n-tiles) + out-cols [16w,16w+16).
// h state: fp32 in registers (D-layout), bf16 XOR-swizzled copy in LDS for
// A-fragment reads by all waves.
// ---------------------------------------------------------------------------
__global__ __launch_bounds__(512, 1) void gru_main(
    const float* __restrict__ c_in,  const float* __restrict__ b_ih,
    const float* __restrict__ b_hh,  const float* __restrict__ b_out,
    const ushort_t* __restrict__ WcB, const ushort_t* __restrict__ W0B,
    const ushort_t* __restrict__ WoB, float* __restrict__ out)
{
  __shared__ __align__(16) ushort_t hbf[4096];   // 16 rows x 256 cols bf16, swizzled
  char* hb = reinterpret_cast<char*>(hbf);

  const int tid = threadIdx.x;
  const int w   = tid >> 6;
  const int l   = tid & 63;
  const int l15 = l & 15;
  const int lg  = l >> 4;
  const int r0  = blockIdx.x << 4;

  float brz_r[2], brz_z[2], b_in_[2], b_hn_[2];
  float hreg[2][4];
#pragma unroll
  for (int ct = 0; ct < 2; ct++){
    int c = w*32 + ct*16 + l15;
    brz_r[ct] = b_ih[c]       + b_hh[c];
    brz_z[ct] = b_ih[256 + c] + b_hh[256 + c];
    b_in_[ct] = b_ih[512 + c];
    b_hn_[ct] = b_hh[512 + c];
#pragma unroll
    for (int i = 0; i < 4; i++){
      int m = lg*4 + i;
      hreg[ct][i] = c_in[(r0 + m)*E + c];
    }
  }
  const float bo = b_out[w*16 + l15];

  // initial h0 -> LDS (bf16, swizzled)
#pragma unroll
  for (int ct = 0; ct < 2; ct++)
#pragma unroll
    for (int i = 0; i < 4; i++){
      int m = lg*4 + i;
      int c = w*32 + ct*16 + l15;
      int cb = (c*2) ^ ((m & 7) << 4);
      *reinterpret_cast<ushort_t*>(hb + m*512 + cb) = f2bf(hreg[ct][i]);
    }
  __syncthreads();

#pragma unroll 1
  for (int k = 0; k < KSTEPS; k++){
    const ushort_t* WB = (k == 0) ? W0B : WcB;
    f32x4 acc[4][2];
#pragma unroll
    for (int g = 0; g < 4; g++)
#pragma unroll
      for (int ct = 0; ct < 2; ct++)
        acc[g][ct] = (f32x4){0.f, 0.f, 0.f, 0.f};
    f32x4 aco = {0.f, 0.f, 0.f, 0.f};

#pragma unroll
    for (int kk = 0; kk < 8; kk++){
      int cb = (kk*64 + lg*16) ^ ((l15 & 7) << 4);
      bf16x8 a = *reinterpret_cast<const bf16x8*>(hb + l15*512 + cb);
#pragma unroll
      for (int g = 0; g < 4; g++){
#pragma unroll
        for (int ct = 0; ct < 2; ct++){
          int tg = g*16 + w*2 + ct;
          bf16x8 b = *reinterpret_cast<const bf16x8*>(WB + ((tg*8 + kk)*64 + l)*8);
          acc[g][ct] = __builtin_amdgcn_mfma_f32_16x16x32_bf16(a, b, acc[g][ct], 0, 0, 0);
        }
      }
      bf16x8 bw = *reinterpret_cast<const bf16x8*>(WoB + ((w*8 + kk)*64 + l)*8);
      aco = __builtin_amdgcn_mfma_f32_16x16x32_bf16(a, bw, aco, 0, 0, 0);
    }

    // out_{k-1} = h_k @ Wout^T + b_out   (y_{k-1} == h_k)
    if (k > 0){
#pragma unroll
      for (int i = 0; i < 4; i++){
        int m = lg*4 + i;
        out[((r0 + m)*KSTEPS + (k - 1))*OUTD + w*16 + l15] = aco[i] + bo;
      }
    }

    // elementwise GRU update, fully in-register (per-lane D-layout match)
#pragma unroll
    for (int ct = 0; ct < 2; ct++){
#pragma unroll
      for (int i = 0; i < 4; i++){
        float r = sigmoid_(acc[0][ct][i] + brz_r[ct]);
        float z = sigmoid_(acc[1][ct][i] + brz_z[ct]);
        float n = tanh_(acc[2][ct][i] + b_in_[ct] + r*(acc[3][ct][i] + b_hn_[ct]));
        hreg[ct][i] = (1.f - z)*n + z*hreg[ct][i];
      }
    }

    __syncthreads();   // all A-frag reads of this step complete
#pragma unroll
    for (int ct = 0; ct < 2; ct++)
#pragma unroll
      for (int i = 0; i < 4; i++){
        int m = lg*4 + i;
        int c = w*32 + ct*16 + l15;
        int cb = (c*2) ^ ((m & 7) << 4);
        *reinterpret_cast<ushort_t*>(hb + m*512 + cb) = f2bf(hreg[ct][i]);
      }
    __syncthreads();   // new h visible to all waves
  }

  // epilogue: out_127 = h_128 @ Wout^T + b_out
  {
    f32x4 aco = {0.f, 0.f, 0.f, 0.f};
#pragma unroll
    for (int kk = 0; kk < 8; kk++){
      int cb = (kk*64 + lg*16) ^ ((l15 & 7) << 4);
      bf16x8 a = *reinterpret_cast<const bf16x8*>(hb + l15*512 + cb);
      bf16x8 bw = *reinterpret_cast<const bf16x8*>(WoB + ((w*8 + kk)*64 + l)*8);
      aco = __builtin_amdgcn_mfma_f32_16x16x32_bf16(a, bw, aco, 0, 0, 0);
    }
#pragma unroll
    for (int i = 0; i < 4; i++){
      int m = lg*4 + i;
      out[((r0 + m)*KSTEPS + 127)*OUTD + w*16 + l15] = aco[i] + bo;
    }
  }
}

extern "C" void kernel_launch(void* const* d_in, const int* in_sizes, int n_in,
                              void* d_out, int out_size, void* d_ws, size_t ws_size,
                              hipStream_t stream)
{
  const float* c     = (const float*)d_in[0];
  const float* W_ih  = (const float*)d_in[1];
  const float* W_hh  = (const float*)d_in[2];
  const float* b_ih  = (const float*)d_in[3];
  const float* b_hh  = (const float*)d_in[4];
  const float* W_out = (const float*)d_in[5];
  const float* b_out = (const float*)d_in[6];

  ushort_t* ws  = (ushort_t*)d_ws;
  ushort_t* WcB = ws;              // 262144 bf16
  ushort_t* W0B = ws + 262144;     // 262144 bf16
  ushort_t* WoB = ws + 524288;     //  32768 bf16

  hipLaunchKernelGGL(prep_weights, dim3(272), dim3(256), 0, stream,
                     W_ih, W_hh, W_out, ws);
  hipLaunchKernelGGL(gru_main, dim3(128), dim3(512), 0, stream,
                     c, b_ih, b_hh, b_out, WcB, W0B, WoB, (float*)d_out);
}

// Round 2
// 714.499 us; speedup vs baseline: 1.5074x; 1.5074x over previous
//
#include <hip/hip_runtime.h>

#define E 256
#define OUTD 128
#define KSTEPS 128

typedef short bf16x8 __attribute__((ext_vector_type(8)));
typedef float f32x4 __attribute__((ext_vector_type(4)));
typedef unsigned short ushort_t;
typedef unsigned int uint_t;

__device__ __forceinline__ ushort_t f2bf(float f){
  union { float f; uint_t u; } v; v.f = f;
  uint_t r = (v.u + 0x7FFFu + ((v.u >> 16) & 1u)) >> 16;
  return (ushort_t)r;
}
__device__ __forceinline__ float sigmoid_(float x){ return 1.f/(1.f + __expf(-x)); }
__device__ __forceinline__ float tanh_(float x){ return 2.f/(1.f + __expf(-2.f*x)) - 1.f; }

// ---------------------------------------------------------------------------
// Prep: build bf16 weight-fragment arrays in ws (unchanged from R1).
//   Wc (steps>=1): [r+z combined | W_ih_n | W_hh_n]  -> G cols [0,1024)
//   W0 (step 0):   [W_hh_r | W_hh_z | 0 | W_hh_n]
//   Wo:            W_out fragments
// Fragment layout: frag(t,kk,l,j) = W[k][c], c = t*16 + (l&15),
//                  k = kk*32 + (l>>4)*8 + j
// ---------------------------------------------------------------------------
__global__ void prep_weights(const float* __restrict__ W_ih,
                             const float* __restrict__ W_hh,
                             const float* __restrict__ W_out,
                             ushort_t* __restrict__ ws)
{
  int fragIdx = blockIdx.x * blockDim.x + threadIdx.x;  // 0..69631
  if (fragIdx >= 69632) return;
  int arr, f;
  if (fragIdx < 32768)      { arr = 0; f = fragIdx; }
  else if (fragIdx < 65536) { arr = 1; f = fragIdx - 32768; }
  else                      { arr = 2; f = fragIdx - 65536; }
  int l  = f & 63;
  int tk = f >> 6;
  int kk = tk & 7;
  int t  = tk >> 3;
  int c  = t*16 + (l & 15);
  int kbase = kk*32 + (l >> 4)*8;
  bf16x8 v8;
#pragma unroll
  for (int j = 0; j < 8; j++){
    int k = kbase + j;
    float v;
    if (arr == 0){
      v = (c < 512) ? (W_ih[c*E + k] + W_hh[c*E + k])
        : (c < 768) ? W_ih[c*E + k]
                    : W_hh[(c-256)*E + k];
    } else if (arr == 1){
      v = (c < 512) ? W_hh[c*E + k]
        : (c < 768) ? 0.f
                    : W_hh[(c-256)*E + k];
    } else {
      v = W_out[c*E + k];
    }
    v8[j] = (short)f2bf(v);
  }
  *reinterpret_cast<bf16x8*>(ws + (size_t)fragIdx * 8) = v8;
}

// ---------------------------------------------------------------------------
// Main persistent kernel: 128 blocks x 512 threads (8 waves), weights resident:
//   VGPR: combined r,z tiles (128 regs) + W_out tile (32 regs) per wave
//   LDS:  all W_ih_n tiles (128 KB, linear, conflict-free b128 reads)
//   L2:   W_hh_n tiles streamed per step (128 KB/step) with 2-deep prefetch
// ---------------------------------------------------------------------------
__global__ __launch_bounds__(512, 2) void gru_main(
    const float* __restrict__ c_in,  const float* __restrict__ b_ih,
    const float* __restrict__ b_hh,  const float* __restrict__ b_out,
    const ushort_t* __restrict__ WcB, const ushort_t* __restrict__ W0B,
    const ushort_t* __restrict__ WoB, float* __restrict__ out)
{
  __shared__ __align__(16) ushort_t lw[65536];   // 16 tiles (W_ih_n) = 128 KB
  __shared__ __align__(16) ushort_t hbf[4096];   // 16 x 256 bf16 h, swizzled
  char* hb = reinterpret_cast<char*>(hbf);

  const int tid = threadIdx.x;
  const int w   = tid >> 6;
  const int l   = tid & 63;
  const int l15 = l & 15;
  const int lg  = l >> 4;
  const int r0  = blockIdx.x << 4;

  float brz_r[2], brz_z[2], b_in_[2], b_hn_[2];
  float hreg[2][4];
#pragma unroll
  for (int ct = 0; ct < 2; ct++){
    int c = w*32 + ct*16 + l15;
    brz_r[ct] = b_ih[c]       + b_hh[c];
    brz_z[ct] = b_ih[256 + c] + b_hh[256 + c];
    b_in_[ct] = b_ih[512 + c];
    b_hn_[ct] = b_hh[512 + c];
#pragma unroll
    for (int i = 0; i < 4; i++){
      int m = lg*4 + i;
      hreg[ct][i] = c_in[(r0 + m)*E + c];
    }
  }
  const float bo = b_out[w*16 + l15];

  // ---- register-resident weights: combined r,z (4 tiles) + W_out (1 tile)
  bf16x8 wrz[4][8];   // [(g*2+ct)][kk], g=0:r g=1:z
#pragma unroll
  for (int g = 0; g < 2; g++)
#pragma unroll
    for (int ct = 0; ct < 2; ct++)
#pragma unroll
      for (int kk = 0; kk < 8; kk++)
        wrz[g*2+ct][kk] = *reinterpret_cast<const bf16x8*>(
            WcB + (((g*16 + w*2 + ct)*8 + kk)*64 + l)*8);
  bf16x8 wo[8];
#pragma unroll
  for (int kk = 0; kk < 8; kk++)
    wo[kk] = *reinterpret_cast<const bf16x8*>(WoB + ((w*8 + kk)*64 + l)*8);

  // ---- W_ih_n tiles (tg 32..47) -> LDS, linear 128 KB copy
  {
    const ushort_t* src = WcB + 32*4096;
#pragma unroll
    for (int i = 0; i < 16; i++){
      int idx = i*512 + tid;   // 16B units
      *reinterpret_cast<bf16x8*>(lw + idx*8) =
          *reinterpret_cast<const bf16x8*>(src + idx*8);
    }
  }

  // ---- initial h0 -> LDS (bf16, swizzled)
#pragma unroll
  for (int ct = 0; ct < 2; ct++)
#pragma unroll
    for (int i = 0; i < 4; i++){
      int m = lg*4 + i;
      int c = w*32 + ct*16 + l15;
      int cb = (c*2) ^ ((m & 7) << 4);
      *reinterpret_cast<ushort_t*>(hb + m*512 + cb) = f2bf(hreg[ct][i]);
    }
  __syncthreads();

#pragma unroll 1
  for (int k = 0; k < KSTEPS; k++){
    f32x4 acc[4][2];
#pragma unroll
    for (int g = 0; g < 4; g++)
#pragma unroll
      for (int ct = 0; ct < 2; ct++)
        acc[g][ct] = (f32x4){0.f, 0.f, 0.f, 0.f};
    f32x4 aco = {0.f, 0.f, 0.f, 0.f};

    if (k == 0){
      // step 0: x=0 -> skip in-part (acc[2]=0); r,z,hn streamed from W0B
#pragma unroll
      for (int kk = 0; kk < 8; kk++){
        int cb = (kk*64 + lg*16) ^ ((l15 & 7) << 4);
        bf16x8 a = *reinterpret_cast<const bf16x8*>(hb + l15*512 + cb);
#pragma unroll
        for (int ct = 0; ct < 2; ct++){
          bf16x8 br = *reinterpret_cast<const bf16x8*>(W0B + (((0*16 + w*2 + ct)*8 + kk)*64 + l)*8);
          bf16x8 bz = *reinterpret_cast<const bf16x8*>(W0B + (((1*16 + w*2 + ct)*8 + kk)*64 + l)*8);
          bf16x8 bn = *reinterpret_cast<const bf16x8*>(W0B + (((3*16 + w*2 + ct)*8 + kk)*64 + l)*8);
          acc[0][ct] = __builtin_amdgcn_mfma_f32_16x16x32_bf16(a, br, acc[0][ct], 0, 0, 0);
          acc[1][ct] = __builtin_amdgcn_mfma_f32_16x16x32_bf16(a, bz, acc[1][ct], 0, 0, 0);
          acc[3][ct] = __builtin_amdgcn_mfma_f32_16x16x32_bf16(a, bn, acc[3][ct], 0, 0, 0);
        }
        aco = __builtin_amdgcn_mfma_f32_16x16x32_bf16(a, wo[kk], aco, 0, 0, 0);
      }
    } else {
      bf16x8 bh[2][2];   // 2-deep prefetch of streamed W_hh_n frags
#pragma unroll
      for (int ct = 0; ct < 2; ct++)
        bh[0][ct] = *reinterpret_cast<const bf16x8*>(
            WcB + (((48 + w*2 + ct)*8 + 0)*64 + l)*8);
#pragma unroll
      for (int kk = 0; kk < 8; kk++){
        int cb = (kk*64 + lg*16) ^ ((l15 & 7) << 4);
        bf16x8 a = *reinterpret_cast<const bf16x8*>(hb + l15*512 + cb);
        if (kk < 7){
#pragma unroll
          for (int ct = 0; ct < 2; ct++)
            bh[(kk+1)&1][ct] = *reinterpret_cast<const bf16x8*>(
                WcB + (((48 + w*2 + ct)*8 + (kk+1))*64 + l)*8);
        }
#pragma unroll
        for (int ct = 0; ct < 2; ct++){
          acc[0][ct] = __builtin_amdgcn_mfma_f32_16x16x32_bf16(a, wrz[ct][kk],   acc[0][ct], 0, 0, 0);
          acc[1][ct] = __builtin_amdgcn_mfma_f32_16x16x32_bf16(a, wrz[2+ct][kk], acc[1][ct], 0, 0, 0);
          bf16x8 bi = *reinterpret_cast<const bf16x8*>(lw + (((w*2 + ct)*8 + kk)*64 + l)*8);
          acc[2][ct] = __builtin_amdgcn_mfma_f32_16x16x32_bf16(a, bi, acc[2][ct], 0, 0, 0);
          acc[3][ct] = __builtin_amdgcn_mfma_f32_16x16x32_bf16(a, bh[kk&1][ct], acc[3][ct], 0, 0, 0);
        }
        aco = __builtin_amdgcn_mfma_f32_16x16x32_bf16(a, wo[kk], aco, 0, 0, 0);
      }
    }

    // out_{k-1} = h_k @ Wout^T + b_out
    if (k > 0){
#pragma unroll
      for (int i = 0; i < 4; i++){
        int m = lg*4 + i;
        out[((r0 + m)*KSTEPS + (k - 1))*OUTD + w*16 + l15] = aco[i] + bo;
      }
    }

    // elementwise GRU update (in-register, D-layout match)
#pragma unroll
    for (int ct = 0; ct < 2; ct++){
#pragma unroll
      for (int i = 0; i < 4; i++){
        float r = sigmoid_(acc[0][ct][i] + brz_r[ct]);
        float z = sigmoid_(acc[1][ct][i] + brz_z[ct]);
        float n = tanh_(acc[2][ct][i] + b_in_[ct] + r*(acc[3][ct][i] + b_hn_[ct]));
        hreg[ct][i] = (1.f - z)*n + z*hreg[ct][i];
      }
    }

    __syncthreads();   // all A-frag reads of this step complete
#pragma unroll
    for (int ct = 0; ct < 2; ct++)
#pragma unroll
      for (int i = 0; i < 4; i++){
        int m = lg*4 + i;
        int c = w*32 + ct*16 + l15;
        int cb = (c*2) ^ ((m & 7) << 4);
        *reinterpret_cast<ushort_t*>(hb + m*512 + cb) = f2bf(hreg[ct][i]);
      }
    __syncthreads();   // new h visible to all waves
  }

  // epilogue: out_127 = h_128 @ Wout^T + b_out
  {
    f32x4 aco = {0.f, 0.f, 0.f, 0.f};
#pragma unroll
    for (int kk = 0; kk < 8; kk++){
      int cb = (kk*64 + lg*16) ^ ((l15 & 7) << 4);
      bf16x8 a = *reinterpret_cast<const bf16x8*>(hb + l15*512 + cb);
      aco = __builtin_amdgcn_mfma_f32_16x16x32_bf16(a, wo[kk], aco, 0, 0, 0);
    }
#pragma unroll
    for (int i = 0; i < 4; i++){
      int m = lg*4 + i;
      out[((r0 + m)*KSTEPS + 127)*OUTD + w*16 + l15] = aco[i] + bo;
    }
  }
}

extern "C" void kernel_launch(void* const* d_in, const int* in_sizes, int n_in,
                              void* d_out, int out_size, void* d_ws, size_t ws_size,
                              hipStream_t stream)
{
  const float* c     = (const float*)d_in[0];
  const float* W_ih  = (const float*)d_in[1];
  const float* W_hh  = (const float*)d_in[2];
  const float* b_ih  = (const float*)d_in[3];
  const float* b_hh  = (const float*)d_in[4];
  const float* W_out = (const float*)d_in[5];
  const float* b_out = (const float*)d_in[6];

  ushort_t* ws  = (ushort_t*)d_ws;
  ushort_t* WcB = ws;              // 262144 bf16
  ushort_t* W0B = ws + 262144;     // 262144 bf16
  ushort_t* WoB = ws + 524288;     //  32768 bf16

  hipLaunchKernelGGL(prep_weights, dim3(272), dim3(256), 0, stream,
                     W_ih, W_hh, W_out, ws);
  hipLaunchKernelGGL(gru_main, dim3(128), dim3(512), 0, stream,
                     c, b_ih, b_hh, b_out, WcB, W0B, WoB, (float*)d_out);
}